// Round 6
// baseline (734.840 us; speedup 1.0000x reference)
//
#include <hip/hip_runtime.h>
#include <hip/hip_bf16.h>
#include <math.h>

#define T_LEN 512
#define B_SZ  256
#define I_SZ  300
#define H_SZ  64
#define G3    192   // 3H

typedef float    f4v __attribute__((ext_vector_type(4)));
typedef _Float16 h2v __attribute__((ext_vector_type(2)));
typedef _Float16 h4v __attribute__((ext_vector_type(4)));
typedef _Float16 h8v __attribute__((ext_vector_type(8)));

__device__ __forceinline__ float dot2(int w, h2v h, float c) {
#if __has_builtin(__builtin_amdgcn_fdot2)
    return __builtin_amdgcn_fdot2(__builtin_bit_cast(h2v, w), h, c, false);
#else
    h2v wv = __builtin_bit_cast(h2v, w);
    return c + (float)wv.x * (float)h.x + (float)wv.y * (float)h.y;
#endif
}

// ---------------------------------------------------------------------------
// Kernel 1: input projection, f16 MFMA.
//   NEW: M = t (x rows for fixed b are contiguous -> dense 150 KB A-tile),
//   xp layout [d][b][t][g] (dense writes here, linear stream for the scan).
//   K-chunks of 64 (5 iters), XOR-swizzled frag-packed LDS (<=2-way, free).
//   Block: 256 thr / 4 waves; wave tile 64(M) x 96(N); acc 96 regs (AGPR-able).
// ---------------------------------------------------------------------------
#define KC  64
#define NKC 5     // ceil(300/64)

// element (m-pos in tile, k' in chunk) -> packed LDS offset (h16 units)
// k' = kh*32 + kgrp*8 + jj ; swizzle m-pos by kgrp to spread write banks.
__device__ __forceinline__ int stage_off(int j, int srow, int skq) {
    int g2 = (skq >> 1) & 3;
    return j * 1024 + (skq >> 3) * 512 + g2 * 128 + ((srow ^ (g2 << 1)) << 3) + (skq & 1) * 4;
}
__device__ __forceinline__ int frag_off(int tile, int kh, int lane) {
    int kgrp = lane >> 4, fr = lane & 15;
    return tile * 1024 + kh * 512 + kgrp * 128 + (((fr ^ (kgrp << 1))) << 3);
}

__global__ __launch_bounds__(256, 2) void proj_gemm(
    const float* __restrict__ x,
    const float* __restrict__ Wf, const float* __restrict__ bf,
    const float* __restrict__ Wb, const float* __restrict__ bb,
    _Float16* __restrict__ xp)
{
    __shared__ _Float16 Ap[8 * 1024];    // 16 KB  (8 m-tiles x 2 kh x 512)
    __shared__ _Float16 Bp[12 * 1024];   // 24 KB  (12 n-tiles)

    const int tid = threadIdx.x;
    const int bid = blockIdx.x;          // 0..2047 ; b fastest -> W shared in L2
    const int d   = bid >> 10;
    const int tb  = (bid >> 8) & 3;      // t-block (128 t's)
    const int b   = bid & 255;

    const float* W    = d ? Wb : Wf;
    const float* bias = d ? bb : bf;
    const float* xbase = x + ((size_t)b * T_LEN + tb * 128) * I_SZ;

    const int srow = tid >> 4;           // 0..15 (row within 16-row group)
    const int skq  = tid & 15;           // k-quad (k' = skq*4)

    const int lane = tid & 63;
    const int w    = tid >> 6;           // 0..3
    const int wm   = (w & 1) * 64;       // wave M offset
    const int wn   = (w >> 1) * 96;      // wave N offset

    f4v acc[4][6];
    #pragma unroll
    for (int mt = 0; mt < 4; ++mt)
        #pragma unroll
        for (int nt = 0; nt < 6; ++nt) acc[mt][nt] = (f4v)0.f;

    float4 av[8], bv[12];
    // prefetch chunk 0
    {
        const bool valid = (skq * 4) <= 296;
        #pragma unroll
        for (int j = 0; j < 8; ++j)
            av[j] = valid ? *(const float4*)(xbase + (size_t)(j * 16 + srow) * I_SZ + skq * 4)
                          : float4{0.f, 0.f, 0.f, 0.f};
        #pragma unroll
        for (int j = 0; j < 12; ++j)
            bv[j] = valid ? *(const float4*)(W + (size_t)(j * 16 + srow) * I_SZ + skq * 4)
                          : float4{0.f, 0.f, 0.f, 0.f};
    }

    for (int kc = 0; kc < NKC; ++kc) {
        __syncthreads();   // previous chunk's fragment reads done

        // ---- convert + swizzled LDS store ----
        #pragma unroll
        for (int j = 0; j < 8; ++j) {
            h4v c = { (_Float16)av[j].x, (_Float16)av[j].y,
                      (_Float16)av[j].z, (_Float16)av[j].w };
            *(h4v*)&Ap[stage_off(j, srow, skq)] = c;
        }
        #pragma unroll
        for (int j = 0; j < 12; ++j) {
            h4v c = { (_Float16)bv[j].x, (_Float16)bv[j].y,
                      (_Float16)bv[j].z, (_Float16)bv[j].w };
            *(h4v*)&Bp[stage_off(j, srow, skq)] = c;
        }
        __syncthreads();

        // ---- issue next chunk's loads (in flight during MFMA phase) ----
        if (kc + 1 < NKC) {
            const int k0 = (kc + 1) * KC;
            const bool valid = (k0 + skq * 4) <= 296;
            #pragma unroll
            for (int j = 0; j < 8; ++j)
                av[j] = valid ? *(const float4*)(xbase + (size_t)(j * 16 + srow) * I_SZ + k0 + skq * 4)
                              : float4{0.f, 0.f, 0.f, 0.f};
            #pragma unroll
            for (int j = 0; j < 12; ++j)
                bv[j] = valid ? *(const float4*)(W + (size_t)(j * 16 + srow) * I_SZ + k0 + skq * 4)
                              : float4{0.f, 0.f, 0.f, 0.f};
        }

        // ---- fragment loads (conflict-free) + MFMA, kh = 0,1 ----
        #pragma unroll
        for (int kh = 0; kh < 2; ++kh) {
            h8v bh_[6];
            #pragma unroll
            for (int nt = 0; nt < 6; ++nt)
                bh_[nt] = *(const h8v*)&Bp[frag_off((w >> 1) * 6 + nt, kh, lane)];
            #pragma unroll
            for (int mt = 0; mt < 4; ++mt) {
                h8v ah = *(const h8v*)&Ap[frag_off((w & 1) * 4 + mt, kh, lane)];
                #pragma unroll
                for (int nt = 0; nt < 6; ++nt)
                    acc[mt][nt] = __builtin_amdgcn_mfma_f32_16x16x32_f16(ah, bh_[nt], acc[mt][nt], 0, 0, 0);
            }
        }
    }

    // ---- epilogue: bias + paired-lane dword f16 stores (dense rows) ----
    const int col  = lane & 15;
    const int rowq = lane >> 4;
    float bias_v[6];
    #pragma unroll
    for (int nt = 0; nt < 6; ++nt) bias_v[nt] = bias[wn + nt * 16 + col];

    #pragma unroll
    for (int mt = 0; mt < 4; ++mt) {
        #pragma unroll
        for (int reg = 0; reg < 4; ++reg) {
            int t = tb * 128 + wm + mt * 16 + rowq * 4 + reg;
            _Float16* o = xp + ((size_t)(d * B_SZ + b) * T_LEN + t) * G3;
            #pragma unroll
            for (int nt = 0; nt < 6; ++nt) {
                float v  = acc[mt][nt][reg] + bias_v[nt];
                float pv = __shfl_xor(v, 1);          // partner col^1, same row
                if ((lane & 1) == 0) {
                    unsigned lo = (unsigned)__builtin_bit_cast(unsigned short, (_Float16)v);
                    unsigned hi = (unsigned)__builtin_bit_cast(unsigned short, (_Float16)pv);
                    int g = wn + nt * 16 + col;       // even
                    *(unsigned*)(o + g) = (hi << 16) | lo;
                }
            }
        }
    }
}

// ---------------------------------------------------------------------------
// Kernel 2: GRU scan — one wave per (dir,batch), barrier-free.
// __launch_bounds__(64, 1): THE fix — allows ~160 arch VGPRs so W stays in
// real VGPRs (R5: VGPR_Count=68 -> W was in AGPRs, ~96 v_accvgpr_read/step).
// xp is now [d][b][t][g]: per-step reads are a linear 384 B; whole stream
// per block is a contiguous 197 KB.
// ---------------------------------------------------------------------------
#define PF 4

__device__ __forceinline__ float sigm_f(float x) {
    return __builtin_amdgcn_rcpf(1.f + __expf(-x));
}
__device__ __forceinline__ float tanh_f(float x) {
    float a = fabsf(x);
    float e = __expf(2.f * a);
    float t = 1.f - 2.f * __builtin_amdgcn_rcpf(1.f + e);
    return copysignf(t, x);
}

__global__ __launch_bounds__(64, 1) void gru_scan(
    const _Float16* __restrict__ xp,
    const float* __restrict__ Whf, const float* __restrict__ bhf,
    const float* __restrict__ Whb, const float* __restrict__ bhb,
    float* __restrict__ feat)
{
    const int lane = threadIdx.x;
    const int bid  = blockIdx.x;       // 0..511
    const int d    = bid >> 8;
    const int b    = bid & 255;

    const float* Whh = d ? Whb : Whf;
    const float* bhh = d ? bhb : bhf;

    // W_hh rows for this lane's 3 gates, packed f16 pairs held as ints
    int wri[32], wzi[32], wni[32];
    {
        const float2* r0 = (const float2*)(Whh + (size_t)lane * 64);
        const float2* r1 = (const float2*)(Whh + (size_t)(64 + lane) * 64);
        const float2* r2 = (const float2*)(Whh + (size_t)(128 + lane) * 64);
        #pragma unroll
        for (int k = 0; k < 32; ++k) {
            float2 a = r0[k], c = r1[k], e = r2[k];
            wri[k] = __builtin_bit_cast(int, h2v{(_Float16)a.x, (_Float16)a.y});
            wzi[k] = __builtin_bit_cast(int, h2v{(_Float16)c.x, (_Float16)c.y});
            wni[k] = __builtin_bit_cast(int, h2v{(_Float16)e.x, (_Float16)e.y});
        }
    }
    // Launder: block rematerialization; with (64,1) they stay in arch VGPRs.
    #pragma unroll
    for (int k = 0; k < 32; ++k)
        asm volatile("" : "+v"(wri[k]), "+v"(wzi[k]), "+v"(wni[k]));

    const float bhr = bhh[lane], bhz = bhh[64 + lane], bhn = bhh[128 + lane];

    __shared__ _Float16 h16s[64];
    h16s[lane] = (_Float16)0.f;
    float hreg = 0.f;
    __syncthreads();

    const int sstep = d ? -G3 : G3;
    const _Float16* xb0 = xp + ((size_t)(d * B_SZ + b) * T_LEN + (d ? T_LEN - 1 : 0)) * G3;

    _Float16 pr[PF], pz[PF], pn[PF];
    #pragma unroll
    for (int j = 0; j < PF; ++j) {
        const _Float16* p = xb0 + j * sstep;
        pr[j] = p[lane]; pz[j] = p[64 + lane]; pn[j] = p[128 + lane];
    }
    const _Float16* pf = xb0 + PF * sstep;

    const h2v* hp = (const h2v*)h16s;

    for (int sb = 0; sb < T_LEN; sb += PF) {
        #pragma unroll
        for (int j = 0; j < PF; ++j) {
            const int s = sb + j;
            float xr = (float)pr[j], xz = (float)pz[j], xn = (float)pn[j];
            if (s + PF < T_LEN) {            // uniform branch; refill slot j
                pr[j] = pf[lane]; pz[j] = pf[64 + lane]; pn[j] = pf[128 + lane];
            }
            pf += sstep;

            float ar0 = 0.f, ar1 = 0.f, az0 = 0.f, az1 = 0.f, an0 = 0.f, an1 = 0.f;
            #pragma unroll
            for (int k = 0; k < 32; k += 2) {
                h2v h0 = hp[k], h1 = hp[k + 1];   // uniform ds_read_b32
                ar0 = dot2(wri[k],     h0, ar0);
                az0 = dot2(wzi[k],     h0, az0);
                an0 = dot2(wni[k],     h0, an0);
                ar1 = dot2(wri[k + 1], h1, ar1);
                az1 = dot2(wzi[k + 1], h1, az1);
                an1 = dot2(wni[k + 1], h1, an1);
            }
            float r  = sigm_f(xr + bhr + ar0 + ar1);
            float z  = sigm_f(xz + bhz + az0 + az1);
            float hn = bhn + an0 + an1;
            float n  = tanh_f(xn + r * hn);
            hreg = (1.f - z) * n + z * hreg;
            h16s[lane] = (_Float16)hreg;       // single-wave: no barrier needed
            if (s == 0)         feat[b * 256 + (d ? 192 : 0) + lane] = hreg;
            if (s == T_LEN - 1) feat[b * 256 + (d ? 64 : 128) + lane] = hreg;
        }
    }
}

// ---------------------------------------------------------------------------
// Kernel 3: MLP head. feat[b][256] -> 32 (LeakyReLU) -> 1
// ---------------------------------------------------------------------------
__global__ __launch_bounds__(64) void head_k(
    const float* __restrict__ feat,
    const float* __restrict__ W1, const float* __restrict__ b1,
    const float* __restrict__ W2, const float* __restrict__ b2,
    float* __restrict__ out)
{
    __shared__ float fs[256];
    const int b = blockIdx.x;
    const int tid = threadIdx.x;
    *(float4*)&fs[tid * 4] = *(const float4*)&feat[b * 256 + tid * 4];
    __syncthreads();
    float v = 0.f;
    if (tid < 32) {
        float a = b1[tid];
        const float4* Wv = (const float4*)(W1 + tid * 256);
        const float4* fv = (const float4*)fs;
        #pragma unroll 8
        for (int k = 0; k < 64; ++k) {
            float4 wv = Wv[k], f = fv[k];
            a += wv.x * f.x + wv.y * f.y + wv.z * f.z + wv.w * f.w;
        }
        a = a >= 0.f ? a : 0.01f * a;
        v = a * W2[tid];
    }
    #pragma unroll
    for (int off = 16; off > 0; off >>= 1) v += __shfl_down(v, off);
    if (tid == 0) out[b] = v + b2[0];
}

// ---------------------------------------------------------------------------
extern "C" void kernel_launch(void* const* d_in, const int* in_sizes, int n_in,
                              void* d_out, int out_size, void* d_ws, size_t ws_size,
                              hipStream_t stream)
{
    const float* x    = (const float*)d_in[0];
    const float* Wihf = (const float*)d_in[1];
    const float* Whhf = (const float*)d_in[2];
    const float* bihf = (const float*)d_in[3];
    const float* bhhf = (const float*)d_in[4];
    const float* Wihb = (const float*)d_in[5];
    const float* Whhb = (const float*)d_in[6];
    const float* bihb = (const float*)d_in[7];
    const float* bhhb = (const float*)d_in[8];
    const float* W1   = (const float*)d_in[9];
    const float* b1   = (const float*)d_in[10];
    const float* W2   = (const float*)d_in[11];
    const float* b2   = (const float*)d_in[12];
    float* out = (float*)d_out;

    _Float16* xp16 = (_Float16*)d_ws;                        // [d][b][t][g] f16, 100.7 MB
    float*    feat = (float*)((char*)d_ws + (size_t)2 * B_SZ * T_LEN * G3 * 2);

    proj_gemm<<<2048, 256, 0, stream>>>(x, Wihf, bihf, Wihb, bihb, xp16);
    gru_scan<<<512, 64, 0, stream>>>(xp16, Whhf, bhhf, Whhb, bhhb, feat);
    head_k<<<256, 64, 0, stream>>>(feat, W1, b1, W2, b2, out);
}